// Round 4
// baseline (266.023 us; speedup 1.0000x reference)
//
#include <hip/hip_runtime.h>

#define KE_CONST 14.3996454784255f

#define P2_SHIFT 14
#define P2_CHUNK 16384            // 64 KB LDS accumulator per chunk
#define NB_BIN   1024             // bin blocks (x4 waves = 4096 wave streams)
#define CAP      256              // records per (wave, bucket) segment
#define CAP_SHIFT 8
#define B2_ACC   36               // accumulator blocks per chunk (252 total = 1/CU)
#define MAXC     8

// ---------------- node precompute: { Zf, Zf^0.3, covrad[Z], 0 }; zero out ----------------
__global__ void zbl_node_prep(const float* __restrict__ node_attrs,
                              const int* __restrict__ atomic_numbers,
                              const float* __restrict__ covalent_radii,
                              float4* __restrict__ node_data,
                              float* __restrict__ out_zero_or_null,
                              int n_nodes, int n_elem) {
    int n = blockIdx.x * blockDim.x + threadIdx.x;
    if (n >= n_nodes) return;
    const float* row = node_attrs + (size_t)n * n_elem;
    float best = row[0];
    int bi = 0;
    for (int i = 1; i < n_elem; ++i) {
        float v = row[i];
        if (v > best) { best = v; bi = i; }
    }
    int Z = atomic_numbers[bi];
    float zf = (float)Z;
    float zp = __powf(zf, 0.3f);
    float cr = covalent_radii[Z];
    node_data[n] = make_float4(zf, zp, cr, 0.0f);
    if (out_zero_or_null) out_zero_or_null[n] = 0.0f;
}

// ---------------- per-edge math ----------------
__device__ __forceinline__ float zbl_val(float xv, const float4& du, const float4& dv,
                                         float rmax) {
    const float inv_a_pref = 1.0f / (0.4543f * 0.529f);
    float t = xv * (du.y + dv.y) * inv_a_pref;
    float phi = 0.1818f  * __expf(-3.2f    * t)
              + 0.5099f  * __expf(-0.9423f * t)
              + 0.2802f  * __expf(-0.4028f * t)
              + 0.02817f * __expf(-0.2016f * t);
    float v = KE_CONST * du.x * dv.x * phi / xv;
    float rr = xv / rmax;
    float r2 = rr * rr;
    float r6 = r2 * r2 * r2;
    float env = 1.0f - 28.0f * r6 + 48.0f * r6 * rr - 21.0f * r6 * r2;
    return 0.5f * v * env;
}

// ---------------- pass 1: dense compute + wave-private register-offset binning ----------------
// Each wave owns C private CAP-record segments. Offsets are wave-uniform registers
// (no LDS, no atomics, no shuffles). Rare segment overflow -> global atomic into out.
template<int C>
__global__ __launch_bounds__(256)
void zbl_bin2(const float* __restrict__ x,
              const int* __restrict__ ei,
              const float4* __restrict__ nd,
              uint2* __restrict__ pairs,
              unsigned* __restrict__ cnt,
              float* __restrict__ out,
              int n_edges, int W) {
    int wave = (blockIdx.x << 2) + (threadIdx.x >> 6);
    int lane = threadIdx.x & 63;
    long long e0 = (long long)wave * n_edges / W;
    long long e1 = (long long)(wave + 1) * n_edges / W;

    unsigned offs[C];
    #pragma unroll
    for (int b = 0; b < C; ++b) offs[b] = 0;

    const int* __restrict__ rcv = ei + n_edges;
    unsigned long long lt_mask = (lane == 63) ? ~0ULL >> 1 : ((1ULL << ((lane & 63) + 0)) - 1ULL);
    // (1ULL << lane) - 1 is fine for lane<64; rewrite plainly:
    lt_mask = (1ULL << lane) - 1ULL;

    for (long long base = e0; base < e1; base += 64) {
        long long e = base + lane;
        bool valid = (e < e1);
        long long ec = valid ? e : (e1 - 1);
        int r = rcv[ec];
        int s = ei[ec];
        float xv = x[ec];
        float4 du = nd[s];
        float4 dv = nd[r];
        float rmax = du.z + dv.z;
        bool keep = valid && (xv < rmax);
        float val = zbl_val(xv, du, dv, rmax);   // dense, once
        int bkt = r >> P2_SHIFT;

        #pragma unroll
        for (int b = 0; b < C; ++b) {
            unsigned long long m = __ballot(keep && (bkt == b));
            if (m != 0ULL) {
                if (keep && (bkt == b)) {
                    unsigned rank = offs[b] + (unsigned)__popcll(m & lt_mask);
                    if (rank < CAP) {
                        pairs[((((size_t)wave * C) + b) << CAP_SHIFT) + rank] =
                            make_uint2((unsigned)(r & (P2_CHUNK - 1)), __float_as_uint(val));
                    } else {
                        atomicAdd(&out[r], val);   // rare overflow path
                    }
                }
                offs[b] += (unsigned)__popcll(m);
            }
        }
    }

    if (lane == 0) {
        #pragma unroll
        for (int b = 0; b < C; ++b) {
            unsigned v = offs[b];
            cnt[wave * C + b] = v < CAP ? v : CAP;
        }
    }
}

// ---------------- pass 2: per-wave consumption of segments, LDS accumulate ----------------
__global__ __launch_bounds__(256)
void zbl_accum2(const uint2* __restrict__ pairs,
                const unsigned* __restrict__ cnt,
                float* __restrict__ partial,
                int C, int B2, int W) {
    int c = blockIdx.x / B2;
    int j = blockIdx.x - c * B2;

    __shared__ __align__(16) float acc[P2_CHUNK];
    for (int i = threadIdx.x * 4; i < P2_CHUNK; i += 256 * 4)
        *(float4*)&acc[i] = make_float4(0.f, 0.f, 0.f, 0.f);
    __syncthreads();

    int wv = threadIdx.x >> 6;
    int lane = threadIdx.x & 63;
    int w0 = j * W / B2;
    int w1 = (j + 1) * W / B2;

    for (int w = w0 + wv; w < w1; w += 4) {
        unsigned n = cnt[w * C + c];
        const uint2* __restrict__ seg = pairs + (((size_t)w * C + c) << CAP_SHIFT);
        for (unsigned i = lane; i < n; i += 64) {
            uint2 rec = seg[i];
            atomicAdd(&acc[rec.x], __uint_as_float(rec.y));
        }
    }
    __syncthreads();

    float* p = partial + ((size_t)c * B2 + j) * P2_CHUNK;
    for (int i = threadIdx.x * 4; i < P2_CHUNK; i += 256 * 4)
        *(float4*)(p + i) = *(const float4*)&acc[i];
}

// ---------------- pass 3: reduce partials, ADD into out (out has overflow atomics) ----------------
__global__ void zbl_reduce_p2(const float* __restrict__ partial,
                              float* __restrict__ out,
                              int n_nodes, int B2) {
    int i = blockIdx.x * blockDim.x + threadIdx.x;
    if (i >= n_nodes) return;
    int c = i >> P2_SHIFT;
    int li = i & (P2_CHUNK - 1);
    const float* p = partial + ((size_t)c * B2) * P2_CHUNK + li;
    float s0 = 0.f, s1 = 0.f, s2 = 0.f, s3 = 0.f;
    int j = 0;
    for (; j + 4 <= B2; j += 4) {
        s0 += p[(size_t)(j + 0) * P2_CHUNK];
        s1 += p[(size_t)(j + 1) * P2_CHUNK];
        s2 += p[(size_t)(j + 2) * P2_CHUNK];
        s3 += p[(size_t)(j + 3) * P2_CHUNK];
    }
    for (; j < B2; ++j) s0 += p[(size_t)j * P2_CHUNK];
    out[i] += (s0 + s1) + (s2 + s3);
}

// ---------------- fallback: direct device atomics ----------------
__global__ void zbl_edge_atomic(const float* __restrict__ x,
                                const int* __restrict__ edge_index,
                                const float4* __restrict__ node_data,
                                float* __restrict__ out,
                                int n_edges) {
    int e = blockIdx.x * blockDim.x + threadIdx.x;
    if (e >= n_edges) return;
    int snd = edge_index[e];
    int r = edge_index[n_edges + e];
    float xv = x[e];
    float4 du = node_data[snd];
    float4 dv = node_data[r];
    float rmax = du.z + dv.z;
    if (xv >= rmax) return;
    atomicAdd(&out[r], zbl_val(xv, du, dv, rmax));
}

extern "C" void kernel_launch(void* const* d_in, const int* in_sizes, int n_in,
                              void* d_out, int out_size, void* d_ws, size_t ws_size,
                              hipStream_t stream) {
    const float* x              = (const float*)d_in[0];
    const float* node_attrs     = (const float*)d_in[1];
    const int*   edge_index     = (const int*)d_in[2];
    const int*   atomic_numbers = (const int*)d_in[3];
    const float* covalent_radii = (const float*)d_in[4];
    float* out = (float*)d_out;

    int n_edges = in_sizes[0];
    int n_elem  = in_sizes[3];
    int n_nodes = in_sizes[1] / n_elem;

    float4* node_data = (float4*)d_ws;
    size_t nd_bytes = (((size_t)n_nodes * sizeof(float4)) + 255) & ~(size_t)255;

    int C = (n_nodes + P2_CHUNK - 1) >> P2_SHIFT;
    int W = NB_BIN * 4;
    size_t cnt_bytes   = ((size_t)W * C * sizeof(unsigned) + 255) & ~(size_t)255;
    size_t pairs_bytes = (((size_t)W * C) << CAP_SHIFT) * sizeof(uint2);
    pairs_bytes = (pairs_bytes + 255) & ~(size_t)255;
    size_t part_bytes  = (size_t)C * B2_ACC * P2_CHUNK * sizeof(float);
    bool fast = (C >= 1) && (C <= MAXC) &&
                (ws_size >= nd_bytes + cnt_bytes + pairs_bytes + part_bytes);

    if (fast) {
        unsigned* cnt   = (unsigned*)((char*)d_ws + nd_bytes);
        uint2*    pairs = (uint2*)((char*)d_ws + nd_bytes + cnt_bytes);
        float*    part  = (float*)((char*)d_ws + nd_bytes + cnt_bytes + pairs_bytes);

        zbl_node_prep<<<(n_nodes + 255) / 256, 256, 0, stream>>>(
            node_attrs, atomic_numbers, covalent_radii, node_data,
            out, n_nodes, n_elem);   // zeroes out for overflow path

        switch (C) {
            case 1: zbl_bin2<1><<<NB_BIN, 256, 0, stream>>>(x, edge_index, node_data, pairs, cnt, out, n_edges, W); break;
            case 2: zbl_bin2<2><<<NB_BIN, 256, 0, stream>>>(x, edge_index, node_data, pairs, cnt, out, n_edges, W); break;
            case 3: zbl_bin2<3><<<NB_BIN, 256, 0, stream>>>(x, edge_index, node_data, pairs, cnt, out, n_edges, W); break;
            case 4: zbl_bin2<4><<<NB_BIN, 256, 0, stream>>>(x, edge_index, node_data, pairs, cnt, out, n_edges, W); break;
            case 5: zbl_bin2<5><<<NB_BIN, 256, 0, stream>>>(x, edge_index, node_data, pairs, cnt, out, n_edges, W); break;
            case 6: zbl_bin2<6><<<NB_BIN, 256, 0, stream>>>(x, edge_index, node_data, pairs, cnt, out, n_edges, W); break;
            case 7: zbl_bin2<7><<<NB_BIN, 256, 0, stream>>>(x, edge_index, node_data, pairs, cnt, out, n_edges, W); break;
            default: zbl_bin2<8><<<NB_BIN, 256, 0, stream>>>(x, edge_index, node_data, pairs, cnt, out, n_edges, W); break;
        }

        zbl_accum2<<<C * B2_ACC, 256, 0, stream>>>(pairs, cnt, part, C, B2_ACC, W);
        zbl_reduce_p2<<<(n_nodes + 255) / 256, 256, 0, stream>>>(part, out, n_nodes, B2_ACC);
        return;
    }

    // fallback: plain device atomics
    zbl_node_prep<<<(n_nodes + 255) / 256, 256, 0, stream>>>(
        node_attrs, atomic_numbers, covalent_radii, node_data,
        out, n_nodes, n_elem);
    zbl_edge_atomic<<<(n_edges + 255) / 256, 256, 0, stream>>>(
        x, edge_index, node_data, out, n_edges);
}